// Round 1
// baseline (1488.587 us; speedup 1.0000x reference)
//
#include <hip/hip_runtime.h>
#include <stdint.h>

#define HID 64
#define INCH 128
#define NGRAPH 64
#define KEEPP 0.7f

// ---------------- Threefry-2x32 (JAX-compatible, 20 rounds) ----------------
__host__ __device__ inline void tf2x32(uint32_t k0, uint32_t k1,
                                       uint32_t& x0, uint32_t& x1) {
  const uint32_t ks2 = k0 ^ k1 ^ 0x1BD11BDAu;
#define ROTL32(v, d) (((v) << (d)) | ((v) >> (32 - (d))))
#define TF_RND(r) { x0 += x1; x1 = ROTL32(x1, r); x1 ^= x0; }
  x0 += k0; x1 += k1;
  TF_RND(13) TF_RND(15) TF_RND(26) TF_RND(6)
  x0 += k1;  x1 += ks2 + 1u;
  TF_RND(17) TF_RND(29) TF_RND(16) TF_RND(24)
  x0 += ks2; x1 += k0 + 2u;
  TF_RND(13) TF_RND(15) TF_RND(26) TF_RND(6)
  x0 += k0;  x1 += k1 + 3u;
  TF_RND(17) TF_RND(29) TF_RND(16) TF_RND(24)
  x0 += k1;  x1 += ks2 + 4u;
  TF_RND(13) TF_RND(15) TF_RND(26) TF_RND(6)
  x0 += ks2; x1 += k0 + 5u;
#undef TF_RND
#undef ROTL32
}

// jax partitionable random_bits(32): bits = o0 ^ o1 of threefry(key, (hi,lo)=64-bit idx)
__device__ __forceinline__ bool keep_mask(uint32_t k0, uint32_t k1, uint32_t idx) {
  uint32_t x0 = 0u, x1 = idx;
  tf2x32(k0, k1, x0, x1);
  uint32_t bits = x0 ^ x1;
  float u = __uint_as_float((bits >> 9) | 0x3f800000u) - 1.0f;
  return u < KEEPP;
}

// ---------------- degree ----------------
__global__ void k_deg(const int* __restrict__ dst, int E, float* __restrict__ deg) {
  int e = blockIdx.x * blockDim.x + threadIdx.x;
  if (e < E) atomicAdd(&deg[dst[e]], 1.0f);
}

__global__ void k_dinv(float* __restrict__ deg, int N) {
  int i = blockIdx.x * blockDim.x + threadIdx.x;
  if (i < N) deg[i] = rsqrtf(deg[i] + 1.0f);  // in-degree + self-loop
}

// ---------------- GEMM: C[N,64] = A[N,K] @ W[K,64] ----------------
template <int K>
__global__ __launch_bounds__(256) void k_gemm(const float* __restrict__ A,
                                              const float* __restrict__ W,
                                              float* __restrict__ C, int N) {
  __shared__ float sW[K * HID];
  for (int i = threadIdx.x; i < K * HID; i += 256) sW[i] = W[i];
  __syncthreads();
  const int wave = threadIdx.x >> 6;
  const int lane = threadIdx.x & 63;
  const int stride = gridDim.x * 4;
  for (int row = blockIdx.x * 4 + wave; row < N; row += stride) {
    const float* Ar = A + (size_t)row * K;
    float xv0 = Ar[lane];
    float xv1 = (K > 64) ? Ar[64 + lane] : 0.0f;
    float acc = 0.0f;
#pragma unroll
    for (int k = 0; k < 64; ++k)
      acc = fmaf(__shfl(xv0, k), sW[k * HID + lane], acc);
    if (K > 64) {
#pragma unroll
      for (int k = 0; k < 64; ++k)
        acc = fmaf(__shfl(xv1, k), sW[(64 + k) * HID + lane], acc);
    }
    C[(size_t)row * HID + lane] = acc;
  }
}

// ---------------- edge scatter: agg[dst] += tmp[src] * norm ----------------
__global__ __launch_bounds__(256) void k_scatter(const float* __restrict__ tmp,
                                                 const int* __restrict__ src,
                                                 const int* __restrict__ dst,
                                                 const float* __restrict__ dinv,
                                                 float* __restrict__ agg, int E) {
  int e = (int)((blockIdx.x * 256u + threadIdx.x) >> 6);
  int lane = threadIdx.x & 63;
  if (e >= E) return;
  int s = src[e], d = dst[e];
  float w = dinv[s] * dinv[d];
  float v = tmp[(size_t)s * HID + lane] * w;
  atomicAdd(&agg[(size_t)d * HID + lane], v);
}

// ---------------- finalize: self-loop + bias + relu + dropout (in place) ----------------
__global__ __launch_bounds__(256) void k_finalize(float* __restrict__ agg,
                                                  const float* __restrict__ tmp,
                                                  const float* __restrict__ dinv,
                                                  const float* __restrict__ bias,
                                                  int total, uint32_t k0, uint32_t k1) {
  int idx = blockIdx.x * blockDim.x + threadIdx.x;
  if (idx >= total) return;
  int i = idx >> 6, c = idx & 63;
  float di = dinv[i];
  float v = agg[idx] + tmp[idx] * di * di + bias[c];
  v = fmaxf(v, 0.0f);
  v = keep_mask(k0, k1, (uint32_t)idx) ? v / KEEPP : 0.0f;
  agg[idx] = v;
}

// ---------------- mean-pool partials ----------------
__global__ __launch_bounds__(256) void k_pool(const float* __restrict__ h,
                                              const int* __restrict__ batch,
                                              float* __restrict__ sums,
                                              float* __restrict__ cnts, int N) {
  __shared__ float ls[NGRAPH * HID];
  __shared__ float lc[NGRAPH];
  for (int i = threadIdx.x; i < NGRAPH * HID; i += 256) ls[i] = 0.0f;
  if (threadIdx.x < NGRAPH) lc[threadIdx.x] = 0.0f;
  __syncthreads();
  const int lane = threadIdx.x & 63;
  const int wave = threadIdx.x >> 6;
  int per = (N + gridDim.x - 1) / gridDim.x;
  int beg = blockIdx.x * per;
  int end = min(N, beg + per);
  for (int i = beg + wave; i < end; i += 4) {
    int g = batch[i];
    atomicAdd(&ls[g * HID + lane], h[(size_t)i * HID + lane]);
    if (lane == 0) atomicAdd(&lc[g], 1.0f);
  }
  __syncthreads();
  for (int i = threadIdx.x; i < NGRAPH * HID; i += 256)
    if (ls[i] != 0.0f) atomicAdd(&sums[i], ls[i]);
  if (threadIdx.x < NGRAPH && lc[threadIdx.x] != 0.0f)
    atomicAdd(&cnts[threadIdx.x], lc[threadIdx.x]);
}

// ---------------- MLP head (single block) ----------------
__global__ __launch_bounds__(256) void k_head(const float* __restrict__ sums,
                                              const float* __restrict__ cnts,
                                              const float* __restrict__ Wm1,
                                              const float* __restrict__ bm1,
                                              const float* __restrict__ Wm2,
                                              const float* __restrict__ bm2,
                                              float* __restrict__ out,
                                              uint32_t k0, uint32_t k1) {
  __shared__ float pooled[NGRAPH * HID];
  __shared__ float m[NGRAPH * HID];
  for (int i = threadIdx.x; i < NGRAPH * HID; i += 256) {
    int g = i >> 6;
    pooled[i] = sums[i] / fmaxf(cnts[g], 1.0f);
  }
  __syncthreads();
  for (int i = threadIdx.x; i < NGRAPH * HID; i += 256) {
    int g = i >> 6, j = i & 63;
    float acc = bm1[j];
#pragma unroll 8
    for (int k = 0; k < HID; ++k)
      acc = fmaf(pooled[g * HID + k], Wm1[k * HID + j], acc);
    acc = fmaxf(acc, 0.0f);
    m[i] = keep_mask(k0, k1, (uint32_t)i) ? acc / KEEPP : 0.0f;
  }
  __syncthreads();
  if (threadIdx.x < NGRAPH) {
    int g = threadIdx.x;
    float acc = bm2[0];
#pragma unroll 8
    for (int j = 0; j < HID; ++j)
      acc = fmaf(m[g * HID + j], Wm2[j], acc);
    out[g] = acc;
  }
}

extern "C" void kernel_launch(void* const* d_in, const int* in_sizes, int n_in,
                              void* d_out, int out_size, void* d_ws, size_t ws_size,
                              hipStream_t stream) {
  const float* x     = (const float*)d_in[0];
  const int*   ei    = (const int*)d_in[1];
  const int*   batch = (const int*)d_in[2];
  const float* W1 = (const float*)d_in[3];
  const float* b1 = (const float*)d_in[4];
  const float* W2 = (const float*)d_in[5];
  const float* b2 = (const float*)d_in[6];
  const float* W3 = (const float*)d_in[7];
  const float* b3 = (const float*)d_in[8];
  const float* Wm1 = (const float*)d_in[9];
  const float* bm1 = (const float*)d_in[10];
  const float* Wm2 = (const float*)d_in[11];
  const float* bm2 = (const float*)d_in[12];
  float* out = (float*)d_out;

  const int N = in_sizes[0] / INCH;
  const int E = in_sizes[1] / 2;
  const int* src = ei;
  const int* dst = ei + E;

  // workspace layout
  char* ws = (char*)d_ws;
  const size_t buf_bytes = (size_t)N * HID * sizeof(float);
  float* B0   = (float*)ws;                       // tmp = h @ W
  float* B1   = (float*)(ws + buf_bytes);         // agg -> h_next
  float* deg  = (float*)(ws + 2 * buf_bytes);     // deg -> deg_inv_sqrt (in place)
  float* sums = deg + N;                          // [64,64]
  float* cnts = sums + NGRAPH * HID;              // [64]

  // dropout keys: dk[i] = threefry2x32((0,42),(0,i))   (partitionable fold-like split)
  uint32_t dk[4][2];
  for (uint32_t i = 0; i < 4; ++i) {
    uint32_t a = 0u, b = i;
    tf2x32(0u, 42u, a, b);
    dk[i][0] = a; dk[i][1] = b;
  }

  const int total = N * HID;

  // degrees
  hipMemsetAsync(deg, 0, (size_t)N * sizeof(float), stream);
  k_deg<<<(E + 255) / 256, 256, 0, stream>>>(dst, E, deg);
  k_dinv<<<(N + 255) / 256, 256, 0, stream>>>(deg, N);

  const int gemm_grid = (N + 3) / 4;
  const int scat_grid = (E + 3) / 4;
  const int fin_grid  = (total + 255) / 256;

  // ---- layer 1 (K=128) ----
  k_gemm<INCH><<<gemm_grid, 256, 0, stream>>>(x, W1, B0, N);
  hipMemsetAsync(B1, 0, buf_bytes, stream);
  k_scatter<<<scat_grid, 256, 0, stream>>>(B0, src, dst, deg, B1, E);
  k_finalize<<<fin_grid, 256, 0, stream>>>(B1, B0, deg, b1, total, dk[0][0], dk[0][1]);

  // ---- layer 2 (K=64) ----
  k_gemm<HID><<<gemm_grid, 256, 0, stream>>>(B1, W2, B0, N);
  hipMemsetAsync(B1, 0, buf_bytes, stream);
  k_scatter<<<scat_grid, 256, 0, stream>>>(B0, src, dst, deg, B1, E);
  k_finalize<<<fin_grid, 256, 0, stream>>>(B1, B0, deg, b2, total, dk[1][0], dk[1][1]);

  // ---- layer 3 (K=64) ----
  k_gemm<HID><<<gemm_grid, 256, 0, stream>>>(B1, W3, B0, N);
  hipMemsetAsync(B1, 0, buf_bytes, stream);
  k_scatter<<<scat_grid, 256, 0, stream>>>(B0, src, dst, deg, B1, E);
  k_finalize<<<fin_grid, 256, 0, stream>>>(B1, B0, deg, b3, total, dk[2][0], dk[2][1]);

  // ---- pool + head ----
  hipMemsetAsync(sums, 0, (NGRAPH * HID + NGRAPH) * sizeof(float), stream);
  k_pool<<<256, 256, 0, stream>>>(B1, batch, sums, cnts, N);
  k_head<<<1, 256, 0, stream>>>(sums, cnts, Wm1, bm1, Wm2, bm2, out,
                                dk[3][0], dk[3][1]);
  (void)n_in; (void)out_size; (void)ws_size;
}

// Round 2
// 933.912 us; speedup vs baseline: 1.5939x; 1.5939x over previous
//
#include <hip/hip_runtime.h>
#include <stdint.h>

#define HID 64
#define INCH 128
#define NGRAPH 64
#define KEEPP 0.7f
#define SCAN_T 1024

// ---------------- Threefry-2x32 (JAX-compatible, 20 rounds) ----------------
__host__ __device__ inline void tf2x32(uint32_t k0, uint32_t k1,
                                       uint32_t& x0, uint32_t& x1) {
  const uint32_t ks2 = k0 ^ k1 ^ 0x1BD11BDAu;
#define ROTL32(v, d) (((v) << (d)) | ((v) >> (32 - (d))))
#define TF_RND(r) { x0 += x1; x1 = ROTL32(x1, r); x1 ^= x0; }
  x0 += k0; x1 += k1;
  TF_RND(13) TF_RND(15) TF_RND(26) TF_RND(6)
  x0 += k1;  x1 += ks2 + 1u;
  TF_RND(17) TF_RND(29) TF_RND(16) TF_RND(24)
  x0 += ks2; x1 += k0 + 2u;
  TF_RND(13) TF_RND(15) TF_RND(26) TF_RND(6)
  x0 += k0;  x1 += k1 + 3u;
  TF_RND(17) TF_RND(29) TF_RND(16) TF_RND(24)
  x0 += k1;  x1 += ks2 + 4u;
  TF_RND(13) TF_RND(15) TF_RND(26) TF_RND(6)
  x0 += ks2; x1 += k0 + 5u;
#undef TF_RND
#undef ROTL32
}

__device__ __forceinline__ bool keep_mask(uint32_t k0, uint32_t k1, uint32_t idx) {
  uint32_t x0 = 0u, x1 = idx;
  tf2x32(k0, k1, x0, x1);
  uint32_t bits = x0 ^ x1;
  float u = __uint_as_float((bits >> 9) | 0x3f800000u) - 1.0f;
  return u < KEEPP;
}

// ---------------- CSR build ----------------
__global__ void k_hist(const int* __restrict__ dst, int E, int* __restrict__ counts) {
  int e = blockIdx.x * blockDim.x + threadIdx.x;
  if (e < E) atomicAdd(&counts[dst[e]], 1);
}

__global__ void k_dinv(const int* __restrict__ counts, float* __restrict__ dinv, int N) {
  int i = blockIdx.x * blockDim.x + threadIdx.x;
  if (i < N) dinv[i] = rsqrtf((float)counts[i] + 1.0f);  // in-degree + self-loop
}

// single-block exclusive scan over N counts -> row_off[N+1], cursor copy
__global__ __launch_bounds__(SCAN_T) void k_scan(const int* __restrict__ counts,
                                                 int* __restrict__ row_off,
                                                 int* __restrict__ cursor, int N) {
  __shared__ int ssum[SCAN_T];
  const int tid = threadIdx.x;
  const int chunk = (N + SCAN_T - 1) / SCAN_T;
  const int beg = tid * chunk;
  const int end = min(N, beg + chunk);
  int s = 0;
  for (int i = beg; i < end; ++i) s += counts[i];
  ssum[tid] = s;
  __syncthreads();
  for (int off = 1; off < SCAN_T; off <<= 1) {
    int v = (tid >= off) ? ssum[tid - off] : 0;
    __syncthreads();
    ssum[tid] += v;
    __syncthreads();
  }
  int prefix = (tid == 0) ? 0 : ssum[tid - 1];
  for (int i = beg; i < end; ++i) {
    row_off[i] = prefix;
    cursor[i] = prefix;
    prefix += counts[i];
  }
  if (tid == SCAN_T - 1) row_off[N] = prefix;
}

__global__ void k_build(const int* __restrict__ src, const int* __restrict__ dst,
                        const float* __restrict__ dinv, int* __restrict__ cursor,
                        int* __restrict__ csr_src, float* __restrict__ csr_w, int E) {
  int e = blockIdx.x * blockDim.x + threadIdx.x;
  if (e >= E) return;
  int s = src[e], d = dst[e];
  int pos = atomicAdd(&cursor[d], 1);
  csr_src[pos] = s;
  csr_w[pos] = dinv[s] * dinv[d];
}

// ---------------- GEMM: C[N,64] = A[N,K] @ W[K,64] ----------------
template <int K>
__global__ __launch_bounds__(256) void k_gemm(const float* __restrict__ A,
                                              const float* __restrict__ W,
                                              float* __restrict__ C, int N) {
  __shared__ float sW[K * HID];
  for (int i = threadIdx.x; i < K * HID; i += 256) sW[i] = W[i];
  __syncthreads();
  const int wave = threadIdx.x >> 6;
  const int lane = threadIdx.x & 63;
  const int stride = gridDim.x * 4;
  for (int row = blockIdx.x * 4 + wave; row < N; row += stride) {
    const float* Ar = A + (size_t)row * K;
    float xv0 = Ar[lane];
    float xv1 = (K > 64) ? Ar[64 + lane] : 0.0f;
    float acc = 0.0f;
#pragma unroll
    for (int k = 0; k < 64; ++k)
      acc = fmaf(__shfl(xv0, k), sW[k * HID + lane], acc);
    if (K > 64) {
#pragma unroll
      for (int k = 0; k < 64; ++k)
        acc = fmaf(__shfl(xv1, k), sW[(64 + k) * HID + lane], acc);
    }
    C[(size_t)row * HID + lane] = acc;
  }
}

// ---------------- fused gather + self-loop + bias + relu + dropout ----------------
__global__ __launch_bounds__(256) void k_gather(const float* __restrict__ tmp,
                                                const int* __restrict__ row_off,
                                                const int* __restrict__ csr_src,
                                                const float* __restrict__ csr_w,
                                                const float* __restrict__ dinv,
                                                const float* __restrict__ bias,
                                                float* __restrict__ outh, int N,
                                                uint32_t k0, uint32_t k1) {
  const int node = blockIdx.x * 4 + (threadIdx.x >> 6);
  const int lane = threadIdx.x & 63;
  if (node >= N) return;
  const int beg = row_off[node];
  const int end = row_off[node + 1];
  float acc = 0.0f;
  int j = beg;
  // 2-wide manual unroll to keep two gathers in flight
  for (; j + 1 < end; j += 2) {
    int s0 = csr_src[j], s1 = csr_src[j + 1];
    float w0 = csr_w[j], w1 = csr_w[j + 1];
    float v0 = tmp[(size_t)s0 * HID + lane];
    float v1 = tmp[(size_t)s1 * HID + lane];
    acc = fmaf(v0, w0, acc);
    acc = fmaf(v1, w1, acc);
  }
  if (j < end) {
    int s0 = csr_src[j];
    acc = fmaf(tmp[(size_t)s0 * HID + lane], csr_w[j], acc);
  }
  const float di = dinv[node];
  const int idx = node * HID + lane;
  float v = acc + tmp[idx] * di * di + bias[lane];
  v = fmaxf(v, 0.0f);
  v = keep_mask(k0, k1, (uint32_t)idx) ? v / KEEPP : 0.0f;
  outh[idx] = v;
}

// ---------------- mean-pool partials ----------------
__global__ __launch_bounds__(256) void k_pool(const float* __restrict__ h,
                                              const int* __restrict__ batch,
                                              float* __restrict__ sums,
                                              float* __restrict__ cnts, int N) {
  __shared__ float ls[NGRAPH * HID];
  __shared__ float lc[NGRAPH];
  for (int i = threadIdx.x; i < NGRAPH * HID; i += 256) ls[i] = 0.0f;
  if (threadIdx.x < NGRAPH) lc[threadIdx.x] = 0.0f;
  __syncthreads();
  const int lane = threadIdx.x & 63;
  const int wave = threadIdx.x >> 6;
  int per = (N + gridDim.x - 1) / gridDim.x;
  int beg = blockIdx.x * per;
  int end = min(N, beg + per);
  for (int i = beg + wave; i < end; i += 4) {
    int g = batch[i];
    atomicAdd(&ls[g * HID + lane], h[(size_t)i * HID + lane]);
    if (lane == 0) atomicAdd(&lc[g], 1.0f);
  }
  __syncthreads();
  for (int i = threadIdx.x; i < NGRAPH * HID; i += 256)
    if (ls[i] != 0.0f) atomicAdd(&sums[i], ls[i]);
  if (threadIdx.x < NGRAPH && lc[threadIdx.x] != 0.0f)
    atomicAdd(&cnts[threadIdx.x], lc[threadIdx.x]);
}

// ---------------- MLP head (single block) ----------------
__global__ __launch_bounds__(256) void k_head(const float* __restrict__ sums,
                                              const float* __restrict__ cnts,
                                              const float* __restrict__ Wm1,
                                              const float* __restrict__ bm1,
                                              const float* __restrict__ Wm2,
                                              const float* __restrict__ bm2,
                                              float* __restrict__ out,
                                              uint32_t k0, uint32_t k1) {
  __shared__ float pooled[NGRAPH * HID];
  __shared__ float m[NGRAPH * HID];
  for (int i = threadIdx.x; i < NGRAPH * HID; i += 256) {
    int g = i >> 6;
    pooled[i] = sums[i] / fmaxf(cnts[g], 1.0f);
  }
  __syncthreads();
  for (int i = threadIdx.x; i < NGRAPH * HID; i += 256) {
    int g = i >> 6, j = i & 63;
    float acc = bm1[j];
#pragma unroll 8
    for (int k = 0; k < HID; ++k)
      acc = fmaf(pooled[g * HID + k], Wm1[k * HID + j], acc);
    acc = fmaxf(acc, 0.0f);
    m[i] = keep_mask(k0, k1, (uint32_t)i) ? acc / KEEPP : 0.0f;
  }
  __syncthreads();
  if (threadIdx.x < NGRAPH) {
    int g = threadIdx.x;
    float acc = bm2[0];
#pragma unroll 8
    for (int j = 0; j < HID; ++j)
      acc = fmaf(m[g * HID + j], Wm2[j], acc);
    out[g] = acc;
  }
}

extern "C" void kernel_launch(void* const* d_in, const int* in_sizes, int n_in,
                              void* d_out, int out_size, void* d_ws, size_t ws_size,
                              hipStream_t stream) {
  const float* x     = (const float*)d_in[0];
  const int*   ei    = (const int*)d_in[1];
  const int*   batch = (const int*)d_in[2];
  const float* W1 = (const float*)d_in[3];
  const float* b1 = (const float*)d_in[4];
  const float* W2 = (const float*)d_in[5];
  const float* b2 = (const float*)d_in[6];
  const float* W3 = (const float*)d_in[7];
  const float* b3 = (const float*)d_in[8];
  const float* Wm1 = (const float*)d_in[9];
  const float* bm1 = (const float*)d_in[10];
  const float* Wm2 = (const float*)d_in[11];
  const float* bm2 = (const float*)d_in[12];
  float* out = (float*)d_out;

  const int N = in_sizes[0] / INCH;
  const int E = in_sizes[1] / 2;
  const int* src = ei;
  const int* dst = ei + E;

  // workspace layout (16B-aligned chunks)
  char* ws = (char*)d_ws;
  const size_t buf_bytes = (size_t)N * HID * sizeof(float);      // 20.48 MB
  size_t off = 0;
  float* B0      = (float*)(ws + off); off += buf_bytes;
  float* B1      = (float*)(ws + off); off += buf_bytes;
  float* dinv    = (float*)(ws + off); off += (size_t)N * 4;
  int*   counts  = (int*)  (ws + off); off += (size_t)N * 4;
  int*   row_off = (int*)  (ws + off); off += ((size_t)N + 4) * 4;
  int*   cursor  = (int*)  (ws + off); off += (size_t)N * 4;
  int*   csr_src = (int*)  (ws + off); off += (size_t)E * 4;
  float* csr_w   = (float*)(ws + off); off += (size_t)E * 4;
  float* sums    = (float*)(ws + off); off += NGRAPH * HID * 4;
  float* cnts    = (float*)(ws + off); off += NGRAPH * 4;

  // dropout keys: dk[i] = threefry2x32((0,42),(0,i))
  uint32_t dk[4][2];
  for (uint32_t i = 0; i < 4; ++i) {
    uint32_t a = 0u, b = i;
    tf2x32(0u, 42u, a, b);
    dk[i][0] = a; dk[i][1] = b;
  }

  // ---- CSR build (reused for all 3 layers) ----
  hipMemsetAsync(counts, 0, (size_t)N * sizeof(int), stream);
  k_hist<<<(E + 255) / 256, 256, 0, stream>>>(dst, E, counts);
  k_dinv<<<(N + 255) / 256, 256, 0, stream>>>(counts, dinv, N);
  k_scan<<<1, SCAN_T, 0, stream>>>(counts, row_off, cursor, N);
  k_build<<<(E + 255) / 256, 256, 0, stream>>>(src, dst, dinv, cursor,
                                               csr_src, csr_w, E);

  const int gemm_grid = 2560;            // stride loop; amortizes W->LDS load
  const int gath_grid = (N + 3) / 4;

  // ---- layer 1 (K=128) ----
  k_gemm<INCH><<<gemm_grid, 256, 0, stream>>>(x, W1, B0, N);
  k_gather<<<gath_grid, 256, 0, stream>>>(B0, row_off, csr_src, csr_w, dinv, b1,
                                          B1, N, dk[0][0], dk[0][1]);
  // ---- layer 2 (K=64) ----
  k_gemm<HID><<<gemm_grid, 256, 0, stream>>>(B1, W2, B0, N);
  k_gather<<<gath_grid, 256, 0, stream>>>(B0, row_off, csr_src, csr_w, dinv, b2,
                                          B1, N, dk[1][0], dk[1][1]);
  // ---- layer 3 (K=64) ----
  k_gemm<HID><<<gemm_grid, 256, 0, stream>>>(B1, W3, B0, N);
  k_gather<<<gath_grid, 256, 0, stream>>>(B0, row_off, csr_src, csr_w, dinv, b3,
                                          B1, N, dk[2][0], dk[2][1]);

  // ---- pool + head ----
  hipMemsetAsync(sums, 0, (NGRAPH * HID + NGRAPH) * sizeof(float), stream);
  k_pool<<<256, 256, 0, stream>>>(B1, batch, sums, cnts, N);
  k_head<<<1, 256, 0, stream>>>(sums, cnts, Wm1, bm1, Wm2, bm2, out,
                                dk[3][0], dk[3][1]);
  (void)n_in; (void)out_size; (void)ws_size;
}

// Round 3
// 786.317 us; speedup vs baseline: 1.8931x; 1.1877x over previous
//
#include <hip/hip_runtime.h>
#include <stdint.h>

#define HID 64
#define INCH 128
#define NGRAPH 64
#define KEEPP 0.7f
#define SCAN_B 256   // elements per scan block

// ---------------- Threefry-2x32 (JAX-compatible, 20 rounds) ----------------
__host__ __device__ inline void tf2x32(uint32_t k0, uint32_t k1,
                                       uint32_t& x0, uint32_t& x1) {
  const uint32_t ks2 = k0 ^ k1 ^ 0x1BD11BDAu;
#define ROTL32(v, d) (((v) << (d)) | ((v) >> (32 - (d))))
#define TF_RND(r) { x0 += x1; x1 = ROTL32(x1, r); x1 ^= x0; }
  x0 += k0; x1 += k1;
  TF_RND(13) TF_RND(15) TF_RND(26) TF_RND(6)
  x0 += k1;  x1 += ks2 + 1u;
  TF_RND(17) TF_RND(29) TF_RND(16) TF_RND(24)
  x0 += ks2; x1 += k0 + 2u;
  TF_RND(13) TF_RND(15) TF_RND(26) TF_RND(6)
  x0 += k0;  x1 += k1 + 3u;
  TF_RND(17) TF_RND(29) TF_RND(16) TF_RND(24)
  x0 += k1;  x1 += ks2 + 4u;
  TF_RND(13) TF_RND(15) TF_RND(26) TF_RND(6)
  x0 += ks2; x1 += k0 + 5u;
#undef TF_RND
#undef ROTL32
}

__device__ __forceinline__ bool keep_mask(uint32_t k0, uint32_t k1, uint32_t idx) {
  uint32_t x0 = 0u, x1 = idx;
  tf2x32(k0, k1, x0, x1);
  uint32_t bits = x0 ^ x1;
  float u = __uint_as_float((bits >> 9) | 0x3f800000u) - 1.0f;
  return u < KEEPP;
}

// ---------------- CSR build ----------------
__global__ void k_hist(const int* __restrict__ dst, int E, int* __restrict__ counts) {
  int e = blockIdx.x * blockDim.x + threadIdx.x;
  if (e < E) atomicAdd(&counts[dst[e]], 1);
}

__global__ void k_dinv(const int* __restrict__ counts, float* __restrict__ dinv, int N) {
  int i = blockIdx.x * blockDim.x + threadIdx.x;
  if (i < N) dinv[i] = rsqrtf((float)counts[i] + 1.0f);  // in-degree + self-loop
}

// ---- two-level scan: (1) block sums ----
__global__ __launch_bounds__(SCAN_B) void k_scan1(const int* __restrict__ counts,
                                                  int* __restrict__ bsum, int N) {
  int i = blockIdx.x * SCAN_B + threadIdx.x;
  int v = (i < N) ? counts[i] : 0;
  // wave reduce (64 lanes) then LDS across 4 waves
  for (int off = 32; off > 0; off >>= 1) v += __shfl_down(v, off);
  __shared__ int ws[4];
  if ((threadIdx.x & 63) == 0) ws[threadIdx.x >> 6] = v;
  __syncthreads();
  if (threadIdx.x == 0) bsum[blockIdx.x] = ws[0] + ws[1] + ws[2] + ws[3];
}

// ---- (2) scan the block sums (B <= 1024) ----
__global__ __launch_bounds__(1024) void k_scan2(const int* __restrict__ bsum,
                                                int* __restrict__ bpre, int B) {
  __shared__ int s[1024];
  int tid = threadIdx.x;
  int v = (tid < B) ? bsum[tid] : 0;
  s[tid] = v;
  __syncthreads();
  for (int off = 1; off < 1024; off <<= 1) {
    int t = (tid >= off) ? s[tid - off] : 0;
    __syncthreads();
    s[tid] += t;
    __syncthreads();
  }
  if (tid < B) bpre[tid] = s[tid] - v;  // exclusive
}

// ---- (3) local scan + offset -> row_off, cursor ----
__global__ __launch_bounds__(SCAN_B) void k_scan3(const int* __restrict__ counts,
                                                  const int* __restrict__ bpre,
                                                  int* __restrict__ row_off,
                                                  int* __restrict__ cursor,
                                                  int N, int E) {
  __shared__ int s[SCAN_B];
  int tid = threadIdx.x;
  int i = blockIdx.x * SCAN_B + tid;
  int v = (i < N) ? counts[i] : 0;
  s[tid] = v;
  __syncthreads();
  for (int off = 1; off < SCAN_B; off <<= 1) {
    int t = (tid >= off) ? s[tid - off] : 0;
    __syncthreads();
    s[tid] += t;
    __syncthreads();
  }
  if (i < N) {
    int excl = bpre[blockIdx.x] + s[tid] - v;
    row_off[i] = excl;
    cursor[i] = excl;
  }
  if (i == 0) row_off[N] = E;  // total edges known analytically
}

__global__ void k_build(const int* __restrict__ src, const int* __restrict__ dst,
                        const float* __restrict__ dinv, int* __restrict__ cursor,
                        int* __restrict__ csr_src, float* __restrict__ csr_w, int E) {
  int e = blockIdx.x * blockDim.x + threadIdx.x;
  if (e >= E) return;
  int s = src[e], d = dst[e];
  int pos = atomicAdd(&cursor[d], 1);
  csr_src[pos] = s;
  csr_w[pos] = dinv[s] * dinv[d];
}

// ---------------- GEMM: C[N,64] = A[N,K] @ W[K,64] ----------------
template <int K>
__global__ __launch_bounds__(256) void k_gemm(const float* __restrict__ A,
                                              const float* __restrict__ W,
                                              float* __restrict__ C, int N) {
  __shared__ float sW[K * HID];
  for (int i = threadIdx.x; i < K * HID; i += 256) sW[i] = W[i];
  __syncthreads();
  const int wave = threadIdx.x >> 6;
  const int lane = threadIdx.x & 63;
  const int stride = gridDim.x * 4;
  for (int row = blockIdx.x * 4 + wave; row < N; row += stride) {
    const float* Ar = A + (size_t)row * K;
    float xv0 = Ar[lane];
    float xv1 = (K > 64) ? Ar[64 + lane] : 0.0f;
    float acc = 0.0f;
#pragma unroll
    for (int k = 0; k < 64; ++k)
      acc = fmaf(__shfl(xv0, k), sW[k * HID + lane], acc);
    if (K > 64) {
#pragma unroll
      for (int k = 0; k < 64; ++k)
        acc = fmaf(__shfl(xv1, k), sW[(64 + k) * HID + lane], acc);
    }
    C[(size_t)row * HID + lane] = acc;
  }
}

// ---------------- fused gather + self-loop + bias + relu + dropout ----------------
__global__ __launch_bounds__(256) void k_gather(const float* __restrict__ tmp,
                                                const int* __restrict__ row_off,
                                                const int* __restrict__ csr_src,
                                                const float* __restrict__ csr_w,
                                                const float* __restrict__ dinv,
                                                const float* __restrict__ bias,
                                                float* __restrict__ outh, int N,
                                                uint32_t k0, uint32_t k1) {
  const int node = blockIdx.x * 4 + (threadIdx.x >> 6);
  const int lane = threadIdx.x & 63;
  if (node >= N) return;
  const int beg = row_off[node];
  const int end = row_off[node + 1];
  float acc = 0.0f;
  int j = beg;
  for (; j + 1 < end; j += 2) {
    int s0 = csr_src[j], s1 = csr_src[j + 1];
    float w0 = csr_w[j], w1 = csr_w[j + 1];
    float v0 = tmp[(size_t)s0 * HID + lane];
    float v1 = tmp[(size_t)s1 * HID + lane];
    acc = fmaf(v0, w0, acc);
    acc = fmaf(v1, w1, acc);
  }
  if (j < end) {
    int s0 = csr_src[j];
    acc = fmaf(tmp[(size_t)s0 * HID + lane], csr_w[j], acc);
  }
  const float di = dinv[node];
  const int idx = node * HID + lane;
  float v = acc + tmp[idx] * di * di + bias[lane];
  v = fmaxf(v, 0.0f);
  v = keep_mask(k0, k1, (uint32_t)idx) ? v / KEEPP : 0.0f;
  outh[idx] = v;
}

// ---------------- mean-pool partials ----------------
__global__ __launch_bounds__(256) void k_pool(const float* __restrict__ h,
                                              const int* __restrict__ batch,
                                              float* __restrict__ sums,
                                              float* __restrict__ cnts, int N) {
  __shared__ float ls[NGRAPH * HID];
  __shared__ float lc[NGRAPH];
  for (int i = threadIdx.x; i < NGRAPH * HID; i += 256) ls[i] = 0.0f;
  if (threadIdx.x < NGRAPH) lc[threadIdx.x] = 0.0f;
  __syncthreads();
  const int lane = threadIdx.x & 63;
  const int wave = threadIdx.x >> 6;
  int per = (N + gridDim.x - 1) / gridDim.x;
  int beg = blockIdx.x * per;
  int end = min(N, beg + per);
  for (int i = beg + wave; i < end; i += 4) {
    int g = batch[i];
    atomicAdd(&ls[g * HID + lane], h[(size_t)i * HID + lane]);
    if (lane == 0) atomicAdd(&lc[g], 1.0f);
  }
  __syncthreads();
  for (int i = threadIdx.x; i < NGRAPH * HID; i += 256)
    if (ls[i] != 0.0f) atomicAdd(&sums[i], ls[i]);
  if (threadIdx.x < NGRAPH && lc[threadIdx.x] != 0.0f)
    atomicAdd(&cnts[threadIdx.x], lc[threadIdx.x]);
}

// ---------------- MLP head (single block) ----------------
__global__ __launch_bounds__(256) void k_head(const float* __restrict__ sums,
                                              const float* __restrict__ cnts,
                                              const float* __restrict__ Wm1,
                                              const float* __restrict__ bm1,
                                              const float* __restrict__ Wm2,
                                              const float* __restrict__ bm2,
                                              float* __restrict__ out,
                                              uint32_t k0, uint32_t k1) {
  __shared__ float pooled[NGRAPH * HID];
  __shared__ float m[NGRAPH * HID];
  for (int i = threadIdx.x; i < NGRAPH * HID; i += 256) {
    int g = i >> 6;
    pooled[i] = sums[i] / fmaxf(cnts[g], 1.0f);
  }
  __syncthreads();
  for (int i = threadIdx.x; i < NGRAPH * HID; i += 256) {
    int g = i >> 6, j = i & 63;
    float acc = bm1[j];
#pragma unroll 8
    for (int k = 0; k < HID; ++k)
      acc = fmaf(pooled[g * HID + k], Wm1[k * HID + j], acc);
    acc = fmaxf(acc, 0.0f);
    m[i] = keep_mask(k0, k1, (uint32_t)i) ? acc / KEEPP : 0.0f;
  }
  __syncthreads();
  if (threadIdx.x < NGRAPH) {
    int g = threadIdx.x;
    float acc = bm2[0];
#pragma unroll 8
    for (int j = 0; j < HID; ++j)
      acc = fmaf(m[g * HID + j], Wm2[j], acc);
    out[g] = acc;
  }
}

extern "C" void kernel_launch(void* const* d_in, const int* in_sizes, int n_in,
                              void* d_out, int out_size, void* d_ws, size_t ws_size,
                              hipStream_t stream) {
  const float* x     = (const float*)d_in[0];
  const int*   ei    = (const int*)d_in[1];
  const int*   batch = (const int*)d_in[2];
  const float* W1 = (const float*)d_in[3];
  const float* b1 = (const float*)d_in[4];
  const float* W2 = (const float*)d_in[5];
  const float* b2 = (const float*)d_in[6];
  const float* W3 = (const float*)d_in[7];
  const float* b3 = (const float*)d_in[8];
  const float* Wm1 = (const float*)d_in[9];
  const float* bm1 = (const float*)d_in[10];
  const float* Wm2 = (const float*)d_in[11];
  const float* bm2 = (const float*)d_in[12];
  float* out = (float*)d_out;

  const int N = in_sizes[0] / INCH;
  const int E = in_sizes[1] / 2;
  const int* src = ei;
  const int* dst = ei + E;
  const int NB = (N + SCAN_B - 1) / SCAN_B;   // scan blocks (<=1024)

  // workspace layout
  char* ws = (char*)d_ws;
  const size_t buf_bytes = (size_t)N * HID * sizeof(float);
  size_t off = 0;
  float* B0      = (float*)(ws + off); off += buf_bytes;
  float* B1      = (float*)(ws + off); off += buf_bytes;
  float* dinv    = (float*)(ws + off); off += (size_t)N * 4;
  int*   counts  = (int*)  (ws + off); off += (size_t)N * 4;
  int*   row_off = (int*)  (ws + off); off += ((size_t)N + 4) * 4;
  int*   cursor  = (int*)  (ws + off); off += (size_t)N * 4;
  int*   bsum    = (int*)  (ws + off); off += 1024 * 4;
  int*   bpre    = (int*)  (ws + off); off += 1024 * 4;
  int*   csr_src = (int*)  (ws + off); off += (size_t)E * 4;
  float* csr_w   = (float*)(ws + off); off += (size_t)E * 4;
  float* sums    = (float*)(ws + off); off += NGRAPH * HID * 4;
  float* cnts    = (float*)(ws + off); off += NGRAPH * 4;

  // dropout keys: dk[i] = threefry2x32((0,42),(0,i))
  uint32_t dk[4][2];
  for (uint32_t i = 0; i < 4; ++i) {
    uint32_t a = 0u, b = i;
    tf2x32(0u, 42u, a, b);
    dk[i][0] = a; dk[i][1] = b;
  }

  // ---- CSR build (reused for all 3 layers) ----
  hipMemsetAsync(counts, 0, (size_t)N * sizeof(int), stream);
  k_hist<<<(E + 255) / 256, 256, 0, stream>>>(dst, E, counts);
  k_dinv<<<(N + 255) / 256, 256, 0, stream>>>(counts, dinv, N);
  k_scan1<<<NB, SCAN_B, 0, stream>>>(counts, bsum, N);
  k_scan2<<<1, 1024, 0, stream>>>(bsum, bpre, NB);
  k_scan3<<<NB, SCAN_B, 0, stream>>>(counts, bpre, row_off, cursor, N, E);
  k_build<<<(E + 255) / 256, 256, 0, stream>>>(src, dst, dinv, cursor,
                                               csr_src, csr_w, E);

  const int gemm_grid = 2560;
  const int gath_grid = (N + 3) / 4;

  // ---- layer 1 (K=128) ----
  k_gemm<INCH><<<gemm_grid, 256, 0, stream>>>(x, W1, B0, N);
  k_gather<<<gath_grid, 256, 0, stream>>>(B0, row_off, csr_src, csr_w, dinv, b1,
                                          B1, N, dk[0][0], dk[0][1]);
  // ---- layer 2 (K=64) ----
  k_gemm<HID><<<gemm_grid, 256, 0, stream>>>(B1, W2, B0, N);
  k_gather<<<gath_grid, 256, 0, stream>>>(B0, row_off, csr_src, csr_w, dinv, b2,
                                          B1, N, dk[1][0], dk[1][1]);
  // ---- layer 3 (K=64) ----
  k_gemm<HID><<<gemm_grid, 256, 0, stream>>>(B1, W3, B0, N);
  k_gather<<<gath_grid, 256, 0, stream>>>(B0, row_off, csr_src, csr_w, dinv, b3,
                                          B1, N, dk[2][0], dk[2][1]);

  // ---- pool + head ----
  hipMemsetAsync(sums, 0, (NGRAPH * HID + NGRAPH) * sizeof(float), stream);
  k_pool<<<256, 256, 0, stream>>>(B1, batch, sums, cnts, N);
  k_head<<<1, 256, 0, stream>>>(sums, cnts, Wm1, bm1, Wm2, bm2, out,
                                dk[3][0], dk[3][1]);
  (void)n_in; (void)out_size; (void)ws_size;
}

// Round 4
// 632.422 us; speedup vs baseline: 2.3538x; 1.2433x over previous
//
#include <hip/hip_runtime.h>
#include <stdint.h>

#define HID 64
#define INCH 128
#define NGRAPH 64
#define KEEPP 0.7f
#define SCAN_B 256   // elements per scan block

// ---------------- Threefry-2x32 (JAX-compatible, 20 rounds) ----------------
__host__ __device__ inline void tf2x32(uint32_t k0, uint32_t k1,
                                       uint32_t& x0, uint32_t& x1) {
  const uint32_t ks2 = k0 ^ k1 ^ 0x1BD11BDAu;
#define ROTL32(v, d) (((v) << (d)) | ((v) >> (32 - (d))))
#define TF_RND(r) { x0 += x1; x1 = ROTL32(x1, r); x1 ^= x0; }
  x0 += k0; x1 += k1;
  TF_RND(13) TF_RND(15) TF_RND(26) TF_RND(6)
  x0 += k1;  x1 += ks2 + 1u;
  TF_RND(17) TF_RND(29) TF_RND(16) TF_RND(24)
  x0 += ks2; x1 += k0 + 2u;
  TF_RND(13) TF_RND(15) TF_RND(26) TF_RND(6)
  x0 += k0;  x1 += k1 + 3u;
  TF_RND(17) TF_RND(29) TF_RND(16) TF_RND(24)
  x0 += k1;  x1 += ks2 + 4u;
  TF_RND(13) TF_RND(15) TF_RND(26) TF_RND(6)
  x0 += ks2; x1 += k0 + 5u;
#undef TF_RND
#undef ROTL32
}

__device__ __forceinline__ bool keep_mask(uint32_t k0, uint32_t k1, uint32_t idx) {
  uint32_t x0 = 0u, x1 = idx;
  tf2x32(k0, k1, x0, x1);
  uint32_t bits = x0 ^ x1;
  float u = __uint_as_float((bits >> 9) | 0x3f800000u) - 1.0f;
  return u < KEEPP;
}

// ---------------- CSR build ----------------
__global__ void k_hist(const int* __restrict__ dst, int E, int* __restrict__ counts) {
  int e = blockIdx.x * blockDim.x + threadIdx.x;
  if (e < E) atomicAdd(&counts[dst[e]], 1);
}

__global__ void k_dinv(const int* __restrict__ counts, float* __restrict__ dinv, int N) {
  int i = blockIdx.x * blockDim.x + threadIdx.x;
  if (i < N) dinv[i] = rsqrtf((float)counts[i] + 1.0f);  // in-degree + self-loop
}

// ---- two-level scan: (1) block sums ----
__global__ __launch_bounds__(SCAN_B) void k_scan1(const int* __restrict__ counts,
                                                  int* __restrict__ bsum, int N) {
  int i = blockIdx.x * SCAN_B + threadIdx.x;
  int v = (i < N) ? counts[i] : 0;
  for (int off = 32; off > 0; off >>= 1) v += __shfl_down(v, off);
  __shared__ int ws[4];
  if ((threadIdx.x & 63) == 0) ws[threadIdx.x >> 6] = v;
  __syncthreads();
  if (threadIdx.x == 0) bsum[blockIdx.x] = ws[0] + ws[1] + ws[2] + ws[3];
}

// ---- (2) scan the block sums (B <= 1024) ----
__global__ __launch_bounds__(1024) void k_scan2(const int* __restrict__ bsum,
                                                int* __restrict__ bpre, int B) {
  __shared__ int s[1024];
  int tid = threadIdx.x;
  int v = (tid < B) ? bsum[tid] : 0;
  s[tid] = v;
  __syncthreads();
  for (int off = 1; off < 1024; off <<= 1) {
    int t = (tid >= off) ? s[tid - off] : 0;
    __syncthreads();
    s[tid] += t;
    __syncthreads();
  }
  if (tid < B) bpre[tid] = s[tid] - v;  // exclusive
}

// ---- (3) local scan + offset -> row_off, cursor ----
__global__ __launch_bounds__(SCAN_B) void k_scan3(const int* __restrict__ counts,
                                                  const int* __restrict__ bpre,
                                                  int* __restrict__ row_off,
                                                  int* __restrict__ cursor,
                                                  int N, int E) {
  __shared__ int s[SCAN_B];
  int tid = threadIdx.x;
  int i = blockIdx.x * SCAN_B + tid;
  int v = (i < N) ? counts[i] : 0;
  s[tid] = v;
  __syncthreads();
  for (int off = 1; off < SCAN_B; off <<= 1) {
    int t = (tid >= off) ? s[tid - off] : 0;
    __syncthreads();
    s[tid] += t;
    __syncthreads();
  }
  if (i < N) {
    int excl = bpre[blockIdx.x] + s[tid] - v;
    row_off[i] = excl;
    cursor[i] = excl;
  }
  if (i == 0) row_off[N] = E;
}

__global__ void k_build(const int* __restrict__ src, const int* __restrict__ dst,
                        const float* __restrict__ dinv, int* __restrict__ cursor,
                        int* __restrict__ csr_src, float* __restrict__ csr_w, int E) {
  int e = blockIdx.x * blockDim.x + threadIdx.x;
  if (e >= E) return;
  int s = src[e], d = dst[e];
  int pos = atomicAdd(&cursor[d], 1);
  csr_src[pos] = s;
  csr_w[pos] = dinv[s] * dinv[d];
}

// ---------------- GEMM: C[N,64] = A[N,K] @ W[K,64] ----------------
// Lane l holds W[:,l] in VGPRs; A-row values are wave-uniform -> scalar loads.
// Inner loop: pure v_fmac(sgpr, vgpr) -- zero DS traffic. 2 rows/iter for ILP.
template <int K>
__global__ __launch_bounds__(256) void k_gemm(const float* __restrict__ A,
                                              const float* __restrict__ W,
                                              float* __restrict__ C, int N) {
  const int lane = threadIdx.x & 63;
  float w[K];
#pragma unroll
  for (int k = 0; k < K; ++k) w[k] = W[k * HID + lane];

  const int gwave = blockIdx.x * 4 + (threadIdx.x >> 6);
  const int nwaves = gridDim.x * 4;
  const int npairs = (N + 1) >> 1;
  for (int p = gwave; p < npairs; p += nwaves) {
    const int r0 = __builtin_amdgcn_readfirstlane(2 * p);
    const bool has1 = (r0 + 1 < N);
    const float* __restrict__ A0 = A + (size_t)r0 * K;
    const float* __restrict__ A1 = A + (size_t)(r0 + (has1 ? 1 : 0)) * K;
    float acc0 = 0.0f, acc1 = 0.0f;
#pragma unroll
    for (int k = 0; k < K; ++k) {
      acc0 = fmaf(A0[k], w[k], acc0);
      acc1 = fmaf(A1[k], w[k], acc1);
    }
    C[(size_t)r0 * HID + lane] = acc0;
    if (has1) C[((size_t)r0 + 1) * HID + lane] = acc1;
  }
}

// ---------------- fused gather + self-loop + bias + relu + dropout ----------------
__global__ __launch_bounds__(256) void k_gather(const float* __restrict__ tmp,
                                                const int* __restrict__ row_off,
                                                const int* __restrict__ csr_src,
                                                const float* __restrict__ csr_w,
                                                const float* __restrict__ dinv,
                                                const float* __restrict__ bias,
                                                float* __restrict__ outh, int N,
                                                uint32_t k0, uint32_t k1) {
  const int node = blockIdx.x * 4 + (threadIdx.x >> 6);
  const int lane = threadIdx.x & 63;
  if (node >= N) return;
  const int beg = row_off[node];
  const int end = row_off[node + 1];
  float acc = 0.0f;
  int j = beg;
  for (; j + 1 < end; j += 2) {
    int s0 = csr_src[j], s1 = csr_src[j + 1];
    float w0 = csr_w[j], w1 = csr_w[j + 1];
    float v0 = tmp[(size_t)s0 * HID + lane];
    float v1 = tmp[(size_t)s1 * HID + lane];
    acc = fmaf(v0, w0, acc);
    acc = fmaf(v1, w1, acc);
  }
  if (j < end) {
    int s0 = csr_src[j];
    acc = fmaf(tmp[(size_t)s0 * HID + lane], csr_w[j], acc);
  }
  const float di = dinv[node];
  const int idx = node * HID + lane;
  float v = acc + tmp[idx] * di * di + bias[lane];
  v = fmaxf(v, 0.0f);
  v = keep_mask(k0, k1, (uint32_t)idx) ? v / KEEPP : 0.0f;
  outh[idx] = v;
}

// ---------------- mean-pool partials ----------------
__global__ __launch_bounds__(256) void k_pool(const float* __restrict__ h,
                                              const int* __restrict__ batch,
                                              float* __restrict__ sums,
                                              float* __restrict__ cnts, int N) {
  __shared__ float ls[NGRAPH * HID];
  __shared__ float lc[NGRAPH];
  for (int i = threadIdx.x; i < NGRAPH * HID; i += 256) ls[i] = 0.0f;
  if (threadIdx.x < NGRAPH) lc[threadIdx.x] = 0.0f;
  __syncthreads();
  const int lane = threadIdx.x & 63;
  const int wave = threadIdx.x >> 6;
  int per = (N + gridDim.x - 1) / gridDim.x;
  int beg = blockIdx.x * per;
  int end = min(N, beg + per);
  for (int i = beg + wave; i < end; i += 4) {
    int g = batch[i];
    atomicAdd(&ls[g * HID + lane], h[(size_t)i * HID + lane]);
    if (lane == 0) atomicAdd(&lc[g], 1.0f);
  }
  __syncthreads();
  for (int i = threadIdx.x; i < NGRAPH * HID; i += 256)
    if (ls[i] != 0.0f) atomicAdd(&sums[i], ls[i]);
  if (threadIdx.x < NGRAPH && lc[threadIdx.x] != 0.0f)
    atomicAdd(&cnts[threadIdx.x], lc[threadIdx.x]);
}

// ---------------- MLP head (single block) ----------------
__global__ __launch_bounds__(256) void k_head(const float* __restrict__ sums,
                                              const float* __restrict__ cnts,
                                              const float* __restrict__ Wm1,
                                              const float* __restrict__ bm1,
                                              const float* __restrict__ Wm2,
                                              const float* __restrict__ bm2,
                                              float* __restrict__ out,
                                              uint32_t k0, uint32_t k1) {
  __shared__ float pooled[NGRAPH * HID];
  __shared__ float m[NGRAPH * HID];
  for (int i = threadIdx.x; i < NGRAPH * HID; i += 256) {
    int g = i >> 6;
    pooled[i] = sums[i] / fmaxf(cnts[g], 1.0f);
  }
  __syncthreads();
  for (int i = threadIdx.x; i < NGRAPH * HID; i += 256) {
    int g = i >> 6, j = i & 63;
    float acc = bm1[j];
#pragma unroll 8
    for (int k = 0; k < HID; ++k)
      acc = fmaf(pooled[g * HID + k], Wm1[k * HID + j], acc);
    acc = fmaxf(acc, 0.0f);
    m[i] = keep_mask(k0, k1, (uint32_t)i) ? acc / KEEPP : 0.0f;
  }
  __syncthreads();
  if (threadIdx.x < NGRAPH) {
    int g = threadIdx.x;
    float acc = bm2[0];
#pragma unroll 8
    for (int j = 0; j < HID; ++j)
      acc = fmaf(m[g * HID + j], Wm2[j], acc);
    out[g] = acc;
  }
}

extern "C" void kernel_launch(void* const* d_in, const int* in_sizes, int n_in,
                              void* d_out, int out_size, void* d_ws, size_t ws_size,
                              hipStream_t stream) {
  const float* x     = (const float*)d_in[0];
  const int*   ei    = (const int*)d_in[1];
  const int*   batch = (const int*)d_in[2];
  const float* W1 = (const float*)d_in[3];
  const float* b1 = (const float*)d_in[4];
  const float* W2 = (const float*)d_in[5];
  const float* b2 = (const float*)d_in[6];
  const float* W3 = (const float*)d_in[7];
  const float* b3 = (const float*)d_in[8];
  const float* Wm1 = (const float*)d_in[9];
  const float* bm1 = (const float*)d_in[10];
  const float* Wm2 = (const float*)d_in[11];
  const float* bm2 = (const float*)d_in[12];
  float* out = (float*)d_out;

  const int N = in_sizes[0] / INCH;
  const int E = in_sizes[1] / 2;
  const int* src = ei;
  const int* dst = ei + E;
  const int NB = (N + SCAN_B - 1) / SCAN_B;

  // workspace layout
  char* ws = (char*)d_ws;
  const size_t buf_bytes = (size_t)N * HID * sizeof(float);
  size_t off = 0;
  float* B0      = (float*)(ws + off); off += buf_bytes;
  float* B1      = (float*)(ws + off); off += buf_bytes;
  float* dinv    = (float*)(ws + off); off += (size_t)N * 4;
  int*   counts  = (int*)  (ws + off); off += (size_t)N * 4;
  int*   row_off = (int*)  (ws + off); off += ((size_t)N + 4) * 4;
  int*   cursor  = (int*)  (ws + off); off += (size_t)N * 4;
  int*   bsum    = (int*)  (ws + off); off += 1024 * 4;
  int*   bpre    = (int*)  (ws + off); off += 1024 * 4;
  int*   csr_src = (int*)  (ws + off); off += (size_t)E * 4;
  float* csr_w   = (float*)(ws + off); off += (size_t)E * 4;
  float* sums    = (float*)(ws + off); off += NGRAPH * HID * 4;
  float* cnts    = (float*)(ws + off); off += NGRAPH * 4;

  // dropout keys: dk[i] = threefry2x32((0,42),(0,i))
  uint32_t dk[4][2];
  for (uint32_t i = 0; i < 4; ++i) {
    uint32_t a = 0u, b = i;
    tf2x32(0u, 42u, a, b);
    dk[i][0] = a; dk[i][1] = b;
  }

  // ---- CSR build (reused for all 3 layers) ----
  hipMemsetAsync(counts, 0, (size_t)N * sizeof(int), stream);
  k_hist<<<(E + 255) / 256, 256, 0, stream>>>(dst, E, counts);
  k_dinv<<<(N + 255) / 256, 256, 0, stream>>>(counts, dinv, N);
  k_scan1<<<NB, SCAN_B, 0, stream>>>(counts, bsum, N);
  k_scan2<<<1, 1024, 0, stream>>>(bsum, bpre, NB);
  k_scan3<<<NB, SCAN_B, 0, stream>>>(counts, bpre, row_off, cursor, N, E);
  k_build<<<(E + 255) / 256, 256, 0, stream>>>(src, dst, dinv, cursor,
                                               csr_src, csr_w, E);

  const int gemm_grid = 2560;
  const int gath_grid = (N + 3) / 4;

  // ---- layer 1 (K=128) ----
  k_gemm<INCH><<<gemm_grid, 256, 0, stream>>>(x, W1, B0, N);
  k_gather<<<gath_grid, 256, 0, stream>>>(B0, row_off, csr_src, csr_w, dinv, b1,
                                          B1, N, dk[0][0], dk[0][1]);
  // ---- layer 2 (K=64) ----
  k_gemm<HID><<<gemm_grid, 256, 0, stream>>>(B1, W2, B0, N);
  k_gather<<<gath_grid, 256, 0, stream>>>(B0, row_off, csr_src, csr_w, dinv, b2,
                                          B1, N, dk[1][0], dk[1][1]);
  // ---- layer 3 (K=64) ----
  k_gemm<HID><<<gemm_grid, 256, 0, stream>>>(B1, W3, B0, N);
  k_gather<<<gath_grid, 256, 0, stream>>>(B0, row_off, csr_src, csr_w, dinv, b3,
                                          B1, N, dk[2][0], dk[2][1]);

  // ---- pool + head ----
  hipMemsetAsync(sums, 0, (NGRAPH * HID + NGRAPH) * sizeof(float), stream);
  k_pool<<<256, 256, 0, stream>>>(B1, batch, sums, cnts, N);
  k_head<<<1, 256, 0, stream>>>(sums, cnts, Wm1, bm1, Wm2, bm2, out,
                                dk[3][0], dk[3][1]);
  (void)n_in; (void)out_size; (void)ws_size;
}